// Round 8
// baseline (969.472 us; speedup 1.0000x reference)
//
#include <hip/hip_runtime.h>
#include <math.h>

#define D 256        // embedding dim
#define P 128        // projection dim
#define K 8192       // num embeddings
#define NTOK 16384   // 16*1024 tokens
#define NROWS (NTOK + K)
#define NCHUNK 8
#define KCHUNK (K / NCHUNK)   // 1024 codes per chunk
#define CAPC 128             // candidate slots per token (expect ~30-50 total)
#define MARGIN 3.0f          // >> 2*bf16 distance error
#define FLT_BIG 3.402823466e+38f

typedef __attribute__((ext_vector_type(8))) short bf16x8;
typedef __attribute__((ext_vector_type(4))) float f32x4;
typedef __attribute__((ext_vector_type(8))) unsigned short u16x8;

__device__ __forceinline__ unsigned short f32_to_bf16_rne(float f) {
    unsigned int u = __float_as_uint(f);
    u = (u + 0x7fffu + ((u >> 16) & 1u)) >> 16;
    return (unsigned short)u;
}

// ---------------------------------------------------------------------------
// Kernel 0: zero-fill the one-hot output region (512 MB), plain float4 stores.
// ---------------------------------------------------------------------------
__global__ __launch_bounds__(256) void zero_kernel(float4* __restrict__ p, size_t n4) {
    size_t i = (size_t)blockIdx.x * blockDim.x + threadIdx.x;
    size_t stride = (size_t)gridDim.x * blockDim.x;
    float4 z; z.x = 0.f; z.y = 0.f; z.z = 0.f; z.w = 0.f;
    for (; i < n4; i += stride) p[i] = z;
}

// ---------------------------------------------------------------------------
// Kernel 1: fused projection. fp32 proj + norms for all rows; bf16 copies:
//   x rows  -> xh row-major (A-side, loaded once per filter block)
//   cb rows -> chs in MFMA-FRAGMENT-CONTIGUOUS order:
//     atom index = (tile64*16 + rowgrp*4 + ks)*64 + quad*16 + l15
//     where code = tile64*64 + rowgrp*16 + l15, k-window = ks*32 + quad*8.
//     => a filter wave's 64 lanes read CONSECUTIVE 16B atoms (coalesced 1KB).
// ARITHMETIC ORDER UNCHANGED (argmin decisions matched numpy with it).
// ---------------------------------------------------------------------------
__global__ __launch_bounds__(256) void proj_kernel(
    const float* __restrict__ x, const float* __restrict__ cb,
    const float* __restrict__ w, const float* __restrict__ bias,
    float* __restrict__ xproj, float* __restrict__ cproj,
    float* __restrict__ xnorm, float* __restrict__ cnorm,
    unsigned short* __restrict__ xh, unsigned short* __restrict__ chs,
    unsigned long long* __restrict__ best, int* __restrict__ cnt)
{
    __shared__ float As[16][D];   // 16 KB
    const int tid = threadIdx.x;
    const int row0 = blockIdx.x * 16;

    {   // init argmin slots + candidate counters (ws is poisoned each call)
        int g = blockIdx.x * 256 + tid;
        if (g < NTOK) { best[g] = 0xFFFFFFFFFFFFFFFFull; cnt[g] = 0; }
    }

    for (int i = tid; i < 16 * (D / 4); i += 256) {
        int r = i / (D / 4);
        int c4 = i % (D / 4);
        int gr = row0 + r;
        const float* src = (gr < NTOK) ? (x + (size_t)gr * D)
                                       : (cb + (size_t)(gr - NTOK) * D);
        float4 v = ((const float4*)src)[c4];
        ((float4*)&As[r][0])[c4] = v;
    }
    __syncthreads();

    const int r = tid >> 4;          // 0..15
    const int c0 = (tid & 15) * 8;   // 0..120

    float acc[8];
#pragma unroll
    for (int j = 0; j < 8; j++) acc[j] = 0.f;

    for (int d = 0; d < D; d += 4) {
        float4 a4 = *(const float4*)&As[r][d];
#pragma unroll
        for (int dd = 0; dd < 4; dd++) {
            float av = (dd == 0) ? a4.x : (dd == 1) ? a4.y : (dd == 2) ? a4.z : a4.w;
            float4 w0 = *(const float4*)&w[(size_t)(d + dd) * P + c0];
            float4 w1 = *(const float4*)&w[(size_t)(d + dd) * P + c0 + 4];
            acc[0] = fmaf(av, w0.x, acc[0]);
            acc[1] = fmaf(av, w0.y, acc[1]);
            acc[2] = fmaf(av, w0.z, acc[2]);
            acc[3] = fmaf(av, w0.w, acc[3]);
            acc[4] = fmaf(av, w1.x, acc[4]);
            acc[5] = fmaf(av, w1.y, acc[5]);
            acc[6] = fmaf(av, w1.z, acc[6]);
            acc[7] = fmaf(av, w1.w, acc[7]);
        }
    }

    float out[8];
    float nrm = 0.f;
    u16x8 hv;
#pragma unroll
    for (int j = 0; j < 8; j++) {
        out[j] = acc[j] + bias[c0 + j];
        nrm = fmaf(out[j], out[j], nrm);
        hv[j] = f32_to_bf16_rne(out[j]);
    }

    const int gr = row0 + r;
    if (gr < NTOK) {
        float* dst = xproj + (size_t)gr * P;
        float4 o0; o0.x = out[0]; o0.y = out[1]; o0.z = out[2]; o0.w = out[3];
        float4 o1; o1.x = out[4]; o1.y = out[5]; o1.z = out[6]; o1.w = out[7];
        *(float4*)&dst[c0] = o0;
        *(float4*)&dst[c0 + 4] = o1;
        *(u16x8*)(xh + (size_t)gr * P + c0) = hv;
    } else {
        int row = gr - NTOK;
        float* dst = cproj + (size_t)row * P;
        float4 o0; o0.x = out[0]; o0.y = out[1]; o0.z = out[2]; o0.w = out[3];
        float4 o1; o1.x = out[4]; o1.y = out[5]; o1.z = out[6]; o1.w = out[7];
        *(float4*)&dst[c0] = o0;
        *(float4*)&dst[c0 + 4] = o1;
        // fragment-contiguous scatter
        int t64 = row >> 6, rg = (row >> 4) & 3, l15 = row & 15;
        int ks = c0 >> 5, quad = (c0 >> 3) & 3;
        size_t atom = ((size_t)(t64 * 16 + rg * 4 + ks) * 4 + quad) * 16 + l15;
        *(u16x8*)(chs + atom * 8) = hv;
    }

#pragma unroll
    for (int off = 1; off < 16; off <<= 1)
        nrm += __shfl_xor(nrm, off, 16);
    if ((tid & 15) == 0) {
        if (gr < NTOK) xnorm[gr] = nrm;
        else           cnorm[gr - NTOK] = nrm;
    }
}

// ---------------------------------------------------------------------------
// Kernel 2: single-pass bf16 MFMA filter. NO LDS staging, NO barriers in the
// loop; B fragments are coalesced 1KB global loads from chs. Per-tile
// butterfly computes the running per-token min; codes within MARGIN of it
// are emitted to cand[] (superset of fp32 argmin: d_bf16(k*) <= run_min+2eps).
// Block = 256 thr (4 waves) = 128 tokens x 1024-code chunk, 16 tiles.
// ---------------------------------------------------------------------------
__global__ __launch_bounds__(256) void filter_kernel(
    const unsigned short* __restrict__ xh, const unsigned short* __restrict__ chs,
    const float* __restrict__ xnorm, const float* __restrict__ cnorm,
    int* __restrict__ cnt, int* __restrict__ cand)
{
    const int tid = threadIdx.x;
    const int tok0 = blockIdx.x * 128;
    const int k0 = blockIdx.y * KCHUNK;

    const int wave = tid >> 6;
    const int lane = tid & 63;
    const int quad = lane >> 4;
    const int l15 = lane & 15;

    bf16x8 afrag[2][4];
#pragma unroll
    for (int mi = 0; mi < 2; mi++)
#pragma unroll
        for (int ks = 0; ks < 4; ks++)
            afrag[mi][ks] = *(const bf16x8*)(
                xh + (size_t)(tok0 + wave * 32 + mi * 16 + l15) * P + ks * 32 + quad * 8);

    float xnv[2][4];
#pragma unroll
    for (int mi = 0; mi < 2; mi++)
#pragma unroll
        for (int r = 0; r < 4; r++)
            xnv[mi][r] = xnorm[tok0 + wave * 32 + mi * 16 + quad * 4 + r];

    float rmin[2][4];
#pragma unroll
    for (int mi = 0; mi < 2; mi++)
#pragma unroll
        for (int r = 0; r < 4; r++) rmin[mi][r] = FLT_BIG;

    for (int ct = 0; ct < KCHUNK / 64; ct++) {
        const int kt = k0 + ct * 64;
        const int t64 = kt >> 6;

        f32x4 acc[2][4];
#pragma unroll
        for (int mi = 0; mi < 2; mi++)
#pragma unroll
            for (int nj = 0; nj < 4; nj++)
                acc[mi][nj] = (f32x4)(0.f);

#pragma unroll
        for (int ks = 0; ks < 4; ks++) {
            // coalesced: 64 lanes read 64 consecutive 16B atoms
            const bf16x8* base = (const bf16x8*)(chs) + (size_t)(t64 * 16 + ks) * 64 + lane;
            bf16x8 b0 = base[0 * 4 * 64];   // rowgrp 0 (codes kt+0..15)
            bf16x8 b1 = base[1 * 4 * 64];   // rowgrp 1
            bf16x8 b2 = base[2 * 4 * 64];   // rowgrp 2
            bf16x8 b3 = base[3 * 4 * 64];   // rowgrp 3
            acc[0][0] = __builtin_amdgcn_mfma_f32_16x16x32_bf16(afrag[0][ks], b0, acc[0][0], 0, 0, 0);
            acc[0][1] = __builtin_amdgcn_mfma_f32_16x16x32_bf16(afrag[0][ks], b1, acc[0][1], 0, 0, 0);
            acc[0][2] = __builtin_amdgcn_mfma_f32_16x16x32_bf16(afrag[0][ks], b2, acc[0][2], 0, 0, 0);
            acc[0][3] = __builtin_amdgcn_mfma_f32_16x16x32_bf16(afrag[0][ks], b3, acc[0][3], 0, 0, 0);
            acc[1][0] = __builtin_amdgcn_mfma_f32_16x16x32_bf16(afrag[1][ks], b0, acc[1][0], 0, 0, 0);
            acc[1][1] = __builtin_amdgcn_mfma_f32_16x16x32_bf16(afrag[1][ks], b1, acc[1][1], 0, 0, 0);
            acc[1][2] = __builtin_amdgcn_mfma_f32_16x16x32_bf16(afrag[1][ks], b2, acc[1][2], 0, 0, 0);
            acc[1][3] = __builtin_amdgcn_mfma_f32_16x16x32_bf16(afrag[1][ks], b3, acc[1][3], 0, 0, 0);
        }

        float cn[4];
#pragma unroll
        for (int nj = 0; nj < 4; nj++) cn[nj] = cnorm[kt + nj * 16 + l15];

#pragma unroll
        for (int mi = 0; mi < 2; mi++)
#pragma unroll
            for (int r = 0; r < 4; r++) {
                float d[4];
#pragma unroll
                for (int nj = 0; nj < 4; nj++)
                    d[nj] = (xnv[mi][r] - 2.0f * acc[mi][nj][r]) + cn[nj];
                float m = fminf(fminf(d[0], d[1]), fminf(d[2], d[3]));
                // min across the 16 l15 lanes (same quad => same token)
#pragma unroll
                for (int off = 1; off < 16; off <<= 1)
                    m = fminf(m, __shfl_xor(m, off));
                float rm = fminf(rmin[mi][r], m);
                rmin[mi][r] = rm;
                float thr = rm + MARGIN;
                const int tok = tok0 + wave * 32 + mi * 16 + quad * 4 + r;
#pragma unroll
                for (int nj = 0; nj < 4; nj++) {
                    if (d[nj] <= thr) {
                        int pos = atomicAdd(&cnt[tok], 1);
                        if (pos < CAPC) cand[(size_t)tok * CAPC + pos] = kt + nj * 16 + l15;
                    }
                }
            }
    }
}

// ---------------------------------------------------------------------------
// Kernel 3: exact fp32 rescore, one wave per token, lane j handles candidates
// j and j+64. Same serial-fma arithmetic/order as all passing rounds.
// Publishes packed (dist_bits<<32 | idx) via u64 atomicMin (tie -> lower idx).
// ---------------------------------------------------------------------------
__global__ __launch_bounds__(256) void rescore_kernel(
    const float* __restrict__ xproj, const float* __restrict__ cproj,
    const float* __restrict__ xnorm, const float* __restrict__ cnorm,
    const int* __restrict__ cnt, const int* __restrict__ cand,
    unsigned long long* __restrict__ best)
{
    const int tid = threadIdx.x;
    const int lane = tid & 63;
    const int wave = tid >> 6;
    const int t = blockIdx.x * 4 + wave;

    int n = cnt[t];
    if (n > CAPC) n = CAPC;
    const float xn = xnorm[t];
    const float* xr = xproj + (size_t)t * P;

    for (int j = lane; j < n; j += 64) {
        int k = cand[(size_t)t * CAPC + j];
        const float* cr = cproj + (size_t)k * P;
        float s = 0.f;
#pragma unroll 8
        for (int p = 0; p < P; p += 4) {
            float4 a = *(const float4*)&xr[p];
            float4 b = *(const float4*)&cr[p];
            s = fmaf(a.x, b.x, s);
            s = fmaf(a.y, b.y, s);
            s = fmaf(a.z, b.z, s);
            s = fmaf(a.w, b.w, s);
        }
        float dist = (xn - 2.0f * s) + cnorm[k];
        unsigned long long pack =
            ((unsigned long long)__float_as_uint(dist) << 32) |
            (unsigned long long)(unsigned)k;
        atomicMin(&best[t], pack);
    }
}

// ---------------------------------------------------------------------------
// Kernel 4: scatter the one-hot 1.0s + gather codebook rows.
// ---------------------------------------------------------------------------
__global__ __launch_bounds__(256) void finalize_kernel(
    const unsigned long long* __restrict__ best, const float* __restrict__ cb,
    float* __restrict__ discrete, float* __restrict__ quant)
{
    __shared__ int sidx[64];
    const int tid = threadIdx.x;
    const int tok0 = blockIdx.x * 64;

    if (tid < 64) {
        int t = tok0 + tid;
        int bi = (int)(best[t] & 0xFFFFFFFFull);
        sidx[tid] = bi;
        discrete[(size_t)t * K + bi] = 1.0f;
    }
    __syncthreads();

    for (int i = tid; i < 64 * (D / 4); i += 256) {
        int t = i >> 6;
        int c4 = i & 63;
        int bi = sidx[t];
        float4 v = ((const float4*)(cb + (size_t)bi * D))[c4];
        ((float4*)(quant + (size_t)(tok0 + t) * D))[c4] = v;
    }
}

// ---------------------------------------------------------------------------
extern "C" void kernel_launch(void* const* d_in, const int* in_sizes, int n_in,
                              void* d_out, int out_size, void* d_ws, size_t ws_size,
                              hipStream_t stream) {
    const float* x    = (const float*)d_in[0];   // [16,1024,256]
    const float* cb   = (const float*)d_in[1];   // [8192,256]
    const float* w    = (const float*)d_in[2];   // [256,128]
    const float* bias = (const float*)d_in[3];   // [128]

    float* out = (float*)d_out;
    float* discrete = out;                               // [16384, 8192]
    float* quant = out + (size_t)NTOK * K;               // [16384, 256]

    char* ws = (char*)d_ws;
    size_t off = 0;
    float* xproj = (float*)(ws + off); off += (size_t)NTOK * P * 4;
    float* cproj = (float*)(ws + off); off += (size_t)K * P * 4;
    float* xnorm = (float*)(ws + off); off += (size_t)NTOK * 4;
    float* cnorm = (float*)(ws + off); off += (size_t)K * 4;
    unsigned short* xh  = (unsigned short*)(ws + off); off += (size_t)NTOK * P * 2;
    unsigned short* chs = (unsigned short*)(ws + off); off += (size_t)K * P * 2;
    int* cnt  = (int*)(ws + off); off += (size_t)NTOK * 4;
    int* cand = (int*)(ws + off); off += (size_t)NTOK * CAPC * 4;
    unsigned long long* best = (unsigned long long*)(ws + off); off += (size_t)NTOK * 8;

    zero_kernel<<<dim3(8192), dim3(256), 0, stream>>>(
        (float4*)discrete, (size_t)NTOK * K / 4);

    proj_kernel<<<dim3(NROWS / 16), dim3(256), 0, stream>>>(
        x, cb, w, bias, xproj, cproj, xnorm, cnorm, xh, chs, best, cnt);

    filter_kernel<<<dim3(NTOK / 128, NCHUNK), dim3(256), 0, stream>>>(
        xh, chs, xnorm, cnorm, cnt, cand);

    rescore_kernel<<<dim3(NTOK / 4), dim3(256), 0, stream>>>(
        xproj, cproj, xnorm, cnorm, cnt, cand, best);

    finalize_kernel<<<dim3(NTOK / 64), dim3(256), 0, stream>>>(
        best, cb, discrete, quant);
}

// Round 9
// 895.485 us; speedup vs baseline: 1.0826x; 1.0826x over previous
//
#include <hip/hip_runtime.h>
#include <math.h>

#define D 256        // embedding dim
#define P 128        // projection dim
#define K 8192       // num embeddings
#define NTOK 16384   // 16*1024 tokens
#define NROWS (NTOK + K)
#define NCHUNK 8
#define KCHUNK (K / NCHUNK)   // 1024 codes per chunk
#define CAPC 128             // candidate slots per token (expect ~16-32)
#define MARGIN 3.0f          // >> 2*bf16 distance error
#define FLT_BIG 3.402823466e+38f

typedef __attribute__((ext_vector_type(8))) short bf16x8;
typedef __attribute__((ext_vector_type(4))) float f32x4;
typedef __attribute__((ext_vector_type(8))) unsigned short u16x8;

__device__ __forceinline__ unsigned short f32_to_bf16_rne(float f) {
    unsigned int u = __float_as_uint(f);
    u = (u + 0x7fffu + ((u >> 16) & 1u)) >> 16;
    return (unsigned short)u;
}

// ---------------------------------------------------------------------------
// Kernel 1: fused projection. fp32 proj + norms; bf16 copies (xh row-major,
// chs in MFMA-fragment-contiguous order). Inits cnt[].
// ARITHMETIC ORDER UNCHANGED (argmin decisions matched numpy, rounds 1-8).
// ---------------------------------------------------------------------------
__global__ __launch_bounds__(256) void proj_kernel(
    const float* __restrict__ x, const float* __restrict__ cb,
    const float* __restrict__ w, const float* __restrict__ bias,
    float* __restrict__ xproj, float* __restrict__ cproj,
    float* __restrict__ xnorm, float* __restrict__ cnorm,
    unsigned short* __restrict__ xh, unsigned short* __restrict__ chs,
    int* __restrict__ cnt)
{
    __shared__ float As[16][D];   // 16 KB
    const int tid = threadIdx.x;
    const int row0 = blockIdx.x * 16;

    {   // init candidate counters (ws is poisoned each call)
        int g = blockIdx.x * 256 + tid;
        if (g < NTOK) cnt[g] = 0;
    }

    for (int i = tid; i < 16 * (D / 4); i += 256) {
        int r = i / (D / 4);
        int c4 = i % (D / 4);
        int gr = row0 + r;
        const float* src = (gr < NTOK) ? (x + (size_t)gr * D)
                                       : (cb + (size_t)(gr - NTOK) * D);
        float4 v = ((const float4*)src)[c4];
        ((float4*)&As[r][0])[c4] = v;
    }
    __syncthreads();

    const int r = tid >> 4;          // 0..15
    const int c0 = (tid & 15) * 8;   // 0..120

    float acc[8];
#pragma unroll
    for (int j = 0; j < 8; j++) acc[j] = 0.f;

    for (int d = 0; d < D; d += 4) {
        float4 a4 = *(const float4*)&As[r][d];
#pragma unroll
        for (int dd = 0; dd < 4; dd++) {
            float av = (dd == 0) ? a4.x : (dd == 1) ? a4.y : (dd == 2) ? a4.z : a4.w;
            float4 w0 = *(const float4*)&w[(size_t)(d + dd) * P + c0];
            float4 w1 = *(const float4*)&w[(size_t)(d + dd) * P + c0 + 4];
            acc[0] = fmaf(av, w0.x, acc[0]);
            acc[1] = fmaf(av, w0.y, acc[1]);
            acc[2] = fmaf(av, w0.z, acc[2]);
            acc[3] = fmaf(av, w0.w, acc[3]);
            acc[4] = fmaf(av, w1.x, acc[4]);
            acc[5] = fmaf(av, w1.y, acc[5]);
            acc[6] = fmaf(av, w1.z, acc[6]);
            acc[7] = fmaf(av, w1.w, acc[7]);
        }
    }

    float out[8];
    float nrm = 0.f;
    u16x8 hv;
#pragma unroll
    for (int j = 0; j < 8; j++) {
        out[j] = acc[j] + bias[c0 + j];
        nrm = fmaf(out[j], out[j], nrm);
        hv[j] = f32_to_bf16_rne(out[j]);
    }

    const int gr = row0 + r;
    if (gr < NTOK) {
        float* dst = xproj + (size_t)gr * P;
        float4 o0; o0.x = out[0]; o0.y = out[1]; o0.z = out[2]; o0.w = out[3];
        float4 o1; o1.x = out[4]; o1.y = out[5]; o1.z = out[6]; o1.w = out[7];
        *(float4*)&dst[c0] = o0;
        *(float4*)&dst[c0 + 4] = o1;
        *(u16x8*)(xh + (size_t)gr * P + c0) = hv;
    } else {
        int row = gr - NTOK;
        float* dst = cproj + (size_t)row * P;
        float4 o0; o0.x = out[0]; o0.y = out[1]; o0.z = out[2]; o0.w = out[3];
        float4 o1; o1.x = out[4]; o1.y = out[5]; o1.z = out[6]; o1.w = out[7];
        *(float4*)&dst[c0] = o0;
        *(float4*)&dst[c0 + 4] = o1;
        int t64 = row >> 6, rg = (row >> 4) & 3, l15 = row & 15;
        int ks = c0 >> 5, quad = (c0 >> 3) & 3;
        size_t atom = ((size_t)(t64 * 16 + rg * 4 + ks) * 4 + quad) * 16 + l15;
        *(u16x8*)(chs + atom * 8) = hv;
    }

#pragma unroll
    for (int off = 1; off < 16; off <<= 1)
        nrm += __shfl_xor(nrm, off, 16);
    if ((tid & 15) == 0) {
        if (gr < NTOK) xnorm[gr] = nrm;
        else           cnorm[gr - NTOK] = nrm;
    }
}

// ---------------------------------------------------------------------------
// Kernel 2: bf16 MFMA filter + FUSED zeroing of the one-hot matrix.
// Block = 256 thr (4 waves) = 128 tokens x 1024-code chunk (16 tiles).
// Each block also zeroes its 512KB slice of `discrete`, 32KB per tile,
// interleaved so the stores hide in the filter's latency bubbles.
// Candidate semantics identical to rounds 3-8 (superset of fp32 argmin).
// ---------------------------------------------------------------------------
__global__ __launch_bounds__(256) void filterz_kernel(
    const unsigned short* __restrict__ xh, const unsigned short* __restrict__ chs,
    const float* __restrict__ xnorm, const float* __restrict__ cnorm,
    int* __restrict__ cnt, int* __restrict__ cand,
    float* __restrict__ discrete)
{
    const int tid = threadIdx.x;
    const int tok0 = blockIdx.x * 128;
    const int k0 = blockIdx.y * KCHUNK;
    const int flat = blockIdx.y * gridDim.x + blockIdx.x;   // 0..1023

    const int wave = tid >> 6;
    const int lane = tid & 63;
    const int quad = lane >> 4;
    const int l15 = lane & 15;

    // zero-slice base (in float4 units): 32768 float4 per block
    f32x4* zbase = (f32x4*)discrete + (size_t)flat * 32768;
    const f32x4 zv = (f32x4)(0.f);

    bf16x8 afrag[2][4];
#pragma unroll
    for (int mi = 0; mi < 2; mi++)
#pragma unroll
        for (int ks = 0; ks < 4; ks++)
            afrag[mi][ks] = *(const bf16x8*)(
                xh + (size_t)(tok0 + wave * 32 + mi * 16 + l15) * P + ks * 32 + quad * 8);

    float xnv[2][4];
#pragma unroll
    for (int mi = 0; mi < 2; mi++)
#pragma unroll
        for (int r = 0; r < 4; r++)
            xnv[mi][r] = xnorm[tok0 + wave * 32 + mi * 16 + quad * 4 + r];

    float rmin[2][4];
#pragma unroll
    for (int mi = 0; mi < 2; mi++)
#pragma unroll
        for (int r = 0; r < 4; r++) rmin[mi][r] = FLT_BIG;

    for (int ct = 0; ct < KCHUNK / 64; ct++) {
        const int kt = k0 + ct * 64;
        const int t64 = kt >> 6;

        // fused zero: 8 coalesced float4 stores per thread per tile
#pragma unroll
        for (int s = 0; s < 8; s++)
            zbase[(size_t)ct * 2048 + s * 256 + tid] = zv;

        f32x4 acc[2][4];
#pragma unroll
        for (int mi = 0; mi < 2; mi++)
#pragma unroll
            for (int nj = 0; nj < 4; nj++)
                acc[mi][nj] = (f32x4)(0.f);

#pragma unroll
        for (int ks = 0; ks < 4; ks++) {
            const bf16x8* base = (const bf16x8*)(chs) + (size_t)(t64 * 16 + ks) * 64 + lane;
            bf16x8 b0 = base[0 * 4 * 64];
            bf16x8 b1 = base[1 * 4 * 64];
            bf16x8 b2 = base[2 * 4 * 64];
            bf16x8 b3 = base[3 * 4 * 64];
            acc[0][0] = __builtin_amdgcn_mfma_f32_16x16x32_bf16(afrag[0][ks], b0, acc[0][0], 0, 0, 0);
            acc[0][1] = __builtin_amdgcn_mfma_f32_16x16x32_bf16(afrag[0][ks], b1, acc[0][1], 0, 0, 0);
            acc[0][2] = __builtin_amdgcn_mfma_f32_16x16x32_bf16(afrag[0][ks], b2, acc[0][2], 0, 0, 0);
            acc[0][3] = __builtin_amdgcn_mfma_f32_16x16x32_bf16(afrag[0][ks], b3, acc[0][3], 0, 0, 0);
            acc[1][0] = __builtin_amdgcn_mfma_f32_16x16x32_bf16(afrag[1][ks], b0, acc[1][0], 0, 0, 0);
            acc[1][1] = __builtin_amdgcn_mfma_f32_16x16x32_bf16(afrag[1][ks], b1, acc[1][1], 0, 0, 0);
            acc[1][2] = __builtin_amdgcn_mfma_f32_16x16x32_bf16(afrag[1][ks], b2, acc[1][2], 0, 0, 0);
            acc[1][3] = __builtin_amdgcn_mfma_f32_16x16x32_bf16(afrag[1][ks], b3, acc[1][3], 0, 0, 0);
        }

        float cn[4];
#pragma unroll
        for (int nj = 0; nj < 4; nj++) cn[nj] = cnorm[kt + nj * 16 + l15];

#pragma unroll
        for (int mi = 0; mi < 2; mi++)
#pragma unroll
            for (int r = 0; r < 4; r++) {
                float d[4];
#pragma unroll
                for (int nj = 0; nj < 4; nj++)
                    d[nj] = (xnv[mi][r] - 2.0f * acc[mi][nj][r]) + cn[nj];
                float m = fminf(fminf(d[0], d[1]), fminf(d[2], d[3]));
#pragma unroll
                for (int off = 1; off < 16; off <<= 1)
                    m = fminf(m, __shfl_xor(m, off));
                float rm = fminf(rmin[mi][r], m);
                rmin[mi][r] = rm;
                float thr = rm + MARGIN;
                const int tok = tok0 + wave * 32 + mi * 16 + quad * 4 + r;
#pragma unroll
                for (int nj = 0; nj < 4; nj++) {
                    if (d[nj] <= thr) {
                        int pos = atomicAdd(&cnt[tok], 1);
                        if (pos < CAPC) cand[(size_t)tok * CAPC + pos] = kt + nj * 16 + l15;
                    }
                }
            }
    }
}

// ---------------------------------------------------------------------------
// Kernel 3: fused exact-fp32 rescore + argmin + one-hot scatter + gather.
// Block = 256 thr = 64 tokens; wave w handles tokens w*16..w*16+15
// sequentially, lanes parallel over candidates. Packed u64 (dist_bits<<32|k)
// butterfly argmin (dist>0 -> monotone bits; tie -> lower idx = jnp.argmin).
// Same serial-fma arithmetic/order as all passing rounds.
// ---------------------------------------------------------------------------
__global__ __launch_bounds__(256) void rescorefinal_kernel(
    const float* __restrict__ xproj, const float* __restrict__ cproj,
    const float* __restrict__ xnorm, const float* __restrict__ cnorm,
    const int* __restrict__ cnt, const int* __restrict__ cand,
    const float* __restrict__ cb,
    float* __restrict__ discrete, float* __restrict__ quant)
{
    __shared__ int sidx[64];
    const int tid = threadIdx.x;
    const int lane = tid & 63;
    const int wave = tid >> 6;
    const int tok0 = blockIdx.x * 64;

    for (int i = 0; i < 16; i++) {
        const int t = tok0 + wave * 16 + i;
        int n = cnt[t];
        if (n > CAPC) n = CAPC;
        const float xn = xnorm[t];
        const float* xr = xproj + (size_t)t * P;

        unsigned long long pack = 0xFFFFFFFFFFFFFFFFull;
        for (int j = lane; j < n; j += 64) {
            int k = cand[(size_t)t * CAPC + j];
            const float* cr = cproj + (size_t)k * P;
            float s = 0.f;
#pragma unroll 8
            for (int p = 0; p < P; p += 4) {
                float4 a = *(const float4*)&xr[p];
                float4 b = *(const float4*)&cr[p];
                s = fmaf(a.x, b.x, s);
                s = fmaf(a.y, b.y, s);
                s = fmaf(a.z, b.z, s);
                s = fmaf(a.w, b.w, s);
            }
            float dist = (xn - 2.0f * s) + cnorm[k];
            unsigned long long pk =
                ((unsigned long long)__float_as_uint(dist) << 32) |
                (unsigned long long)(unsigned)k;
            if (pk < pack) pack = pk;
        }
#pragma unroll
        for (int off = 1; off < 64; off <<= 1) {
            unsigned long long o = __shfl_xor((long long)pack, off);
            if (o < pack) pack = o;
        }
        if (lane == 0) {
            int bi = (int)(pack & 0xFFFFFFFFull);
            sidx[wave * 16 + i] = bi;
            discrete[(size_t)t * K + bi] = 1.0f;
        }
    }
    __syncthreads();

    for (int i = tid; i < 64 * (D / 4); i += 256) {
        int t = i >> 6;
        int c4 = i & 63;
        int bi = sidx[t];
        float4 v = ((const float4*)(cb + (size_t)bi * D))[c4];
        ((float4*)(quant + (size_t)(tok0 + t) * D))[c4] = v;
    }
}

// ---------------------------------------------------------------------------
extern "C" void kernel_launch(void* const* d_in, const int* in_sizes, int n_in,
                              void* d_out, int out_size, void* d_ws, size_t ws_size,
                              hipStream_t stream) {
    const float* x    = (const float*)d_in[0];   // [16,1024,256]
    const float* cb   = (const float*)d_in[1];   // [8192,256]
    const float* w    = (const float*)d_in[2];   // [256,128]
    const float* bias = (const float*)d_in[3];   // [128]

    float* out = (float*)d_out;
    float* discrete = out;                               // [16384, 8192]
    float* quant = out + (size_t)NTOK * K;               // [16384, 256]

    char* ws = (char*)d_ws;
    size_t off = 0;
    float* xproj = (float*)(ws + off); off += (size_t)NTOK * P * 4;
    float* cproj = (float*)(ws + off); off += (size_t)K * P * 4;
    float* xnorm = (float*)(ws + off); off += (size_t)NTOK * 4;
    float* cnorm = (float*)(ws + off); off += (size_t)K * 4;
    unsigned short* xh  = (unsigned short*)(ws + off); off += (size_t)NTOK * P * 2;
    unsigned short* chs = (unsigned short*)(ws + off); off += (size_t)K * P * 2;
    int* cnt  = (int*)(ws + off); off += (size_t)NTOK * 4;
    int* cand = (int*)(ws + off); off += (size_t)NTOK * CAPC * 4;

    proj_kernel<<<dim3(NROWS / 16), dim3(256), 0, stream>>>(
        x, cb, w, bias, xproj, cproj, xnorm, cnorm, xh, chs, cnt);

    filterz_kernel<<<dim3(NTOK / 128, NCHUNK), dim3(256), 0, stream>>>(
        xh, chs, xnorm, cnorm, cnt, cand, discrete);

    rescorefinal_kernel<<<dim3(NTOK / 64), dim3(256), 0, stream>>>(
        xproj, cproj, xnorm, cnorm, cnt, cand, cb, discrete, quant);
}